// Round 8
// baseline (246.544 us; speedup 1.0000x reference)
//
#include <hip/hip_runtime.h>
#include <hip/hip_bf16.h>
#include <math.h>

#define NN 50000
#define NE 800000
#define FIN 256
#define FOUT 32
#define NH 8
#define FE 5
#define AROW 69          // 2*FOUT + FE

typedef float f32x4 __attribute__((ext_vector_type(4)));
typedef short bf16x8 __attribute__((ext_vector_type(8)));

// round-to-nearest-even fp32 -> bf16 bits
static __device__ __forceinline__ unsigned short f2bf(float f) {
    unsigned u = __float_as_uint(f);
    unsigned r = (u + 0x7FFFu + ((u >> 16) & 1u)) >> 16;
    return (unsigned short)r;
}
static __device__ __forceinline__ float bf2f(unsigned short b) {
    return __uint_as_float(((unsigned)b) << 16);
}

// ------------- prep: C matrix + W split tables + s1/s2 column tables --------
// block 0:   Cm[h][k] = a_e[h]·Wew[:,k];  Bs (16 cols: cs<8 -> s1 head cs,
//            cs>=8 -> s2 head cs-8): Bs[cs][k] = sum_o W'[k][h*32+o]*a[h][..o]
// blocks 1..256: Bh/Bl col c = blockIdx-1 (layout [c][k], split bf16 hi/lo)
__global__ __launch_bounds__(256) void k_prep(const float* __restrict__ W,
                                              const float* __restrict__ a,
                                              const float* __restrict__ Wew,
                                              float* __restrict__ C,
                                              unsigned short* __restrict__ Bh,
                                              unsigned short* __restrict__ Bl,
                                              unsigned short* __restrict__ Bsh,
                                              unsigned short* __restrict__ Bsl) {
    int t = threadIdx.x;
    if (blockIdx.x == 0) {
        if (t < NH * FE) {
            int h = t / FE, k = t % FE;
            float s = 0.f;
            for (int j = 0; j < FE; ++j) s += a[h * AROW + 2 * FOUT + j] * Wew[j * FE + k];
            C[t] = s;
        }
        int k = t;   // 0..255
        for (int h = 0; h < NH; ++h) {
            float s1v = 0.f, s2v = 0.f;
            for (int o = 0; o < FOUT; ++o) {
                float wv = W[(size_t)h * (FIN * FOUT) + (size_t)k * FOUT + o];
                s1v += wv * a[h * AROW + o];
                s2v += wv * a[h * AROW + FOUT + o];
            }
            unsigned short h1 = f2bf(s1v);
            Bsh[h * 256 + k] = h1;
            Bsl[h * 256 + k] = f2bf(s1v - bf2f(h1));
            unsigned short h2 = f2bf(s2v);
            Bsh[(8 + h) * 256 + k] = h2;
            Bsl[(8 + h) * 256 + k] = f2bf(s2v - bf2f(h2));
        }
    } else {
        int c = blockIdx.x - 1;      // 0..255
        int k = t;
        int h = c >> 5, o = c & 31;
        float f = W[(size_t)h * (FIN * FOUT) + (size_t)k * FOUT + o];
        unsigned short hi = f2bf(f);
        unsigned short lo = f2bf(f - bf2f(hi));
        Bh[c * 256 + k] = hi;
        Bl[c * 256 + k] = lo;
    }
}

// ------- MFMA GEMM: Wh[n][c] = sum_k x[n][k]*B[k][c], 2-term split-bf16 -----
// s1/s2 computed via 16 extra B-columns (Bs): wave w accumulates the s-tile
// for its row-tile rt=w only (+2 MFMA/k-step, +4 VGPR, no shuffle epilogue).
// Tail: fused edge-count (grid*1024 >= NE) -> kills separate k_count launch.
__global__ __launch_bounds__(256) void k_gemm_mfma(const float* __restrict__ x,
                                                   const unsigned short* __restrict__ Bh,
                                                   const unsigned short* __restrict__ Bl,
                                                   const unsigned short* __restrict__ Bsh,
                                                   const unsigned short* __restrict__ Bsl,
                                                   unsigned short* __restrict__ Whb,
                                                   float* __restrict__ s1,
                                                   float* __restrict__ s2,
                                                   const int* __restrict__ ei,
                                                   int* __restrict__ counts, int nrows) {
    __shared__ __align__(16) unsigned short Ah[64 * 56];  // row stride 56 shorts (112B)
    int t = threadIdx.x;
    int w = t >> 6, l = t & 63;
    int r = l & 15, blk = l >> 4;
    int row0 = blockIdx.x * 64;
    int c0 = w * 64;

    f32x4 acc[4][4];
    f32x4 acc_s = (f32x4)(0.f);
#pragma unroll
    for (int i = 0; i < 4; ++i)
#pragma unroll
        for (int j = 0; j < 4; ++j) acc[i][j] = (f32x4)(0.f);

    int srow = t >> 2, skq = (t & 3) * 8;      // staging: 8 k-elems per thread
    const size_t xrow = (size_t)(row0 + srow) * FIN;

    for (int k0 = 0; k0 < FIN; k0 += 32) {
        // ---- stage A tile (64 rows x 32 k), convert fp32 -> bf16 hi ----
        {
            float v[8];
            if (row0 + srow < nrows) {
                f32x4 u0 = *(const f32x4*)&x[xrow + k0 + skq];
                f32x4 u1 = *(const f32x4*)&x[xrow + k0 + skq + 4];
                v[0] = u0.x; v[1] = u0.y; v[2] = u0.z; v[3] = u0.w;
                v[4] = u1.x; v[5] = u1.y; v[6] = u1.z; v[7] = u1.w;
            } else {
#pragma unroll
                for (int e = 0; e < 8; ++e) v[e] = 0.f;
            }
            bf16x8 hi;
#pragma unroll
            for (int e = 0; e < 8; ++e) hi[e] = (short)f2bf(v[e]);
            *(bf16x8*)&Ah[srow * 56 + skq] = hi;
        }
        __syncthreads();
        bf16x8 ah[4];
#pragma unroll
        for (int rt = 0; rt < 4; ++rt)
            ah[rt] = *(const bf16x8*)&Ah[(rt * 16 + r) * 56 + blk * 8];
#pragma unroll
        for (int ct = 0; ct < 4; ++ct) {
            int c = c0 + ct * 16 + r;
            bf16x8 bh = *(const bf16x8*)&Bh[c * 256 + k0 + blk * 8];
            bf16x8 bl = *(const bf16x8*)&Bl[c * 256 + k0 + blk * 8];
#pragma unroll
            for (int rt = 0; rt < 4; ++rt) {
                acc[rt][ct] = __builtin_amdgcn_mfma_f32_16x16x32_bf16(ah[rt], bh, acc[rt][ct], 0, 0, 0);
                acc[rt][ct] = __builtin_amdgcn_mfma_f32_16x16x32_bf16(ah[rt], bl, acc[rt][ct], 0, 0, 0);
            }
        }
        // ---- s-tile (cols = 16 combined a_src/a_dst projections), rt = w ----
        {
            bf16x8 bsh = *(const bf16x8*)&Bsh[r * 256 + k0 + blk * 8];
            bf16x8 bsl = *(const bf16x8*)&Bsl[r * 256 + k0 + blk * 8];
            acc_s = __builtin_amdgcn_mfma_f32_16x16x32_bf16(ah[w], bsh, acc_s, 0, 0, 0);
            acc_s = __builtin_amdgcn_mfma_f32_16x16x32_bf16(ah[w], bsl, acc_s, 0, 0, 0);
        }
        __syncthreads();
    }

    // ---- write Wh (bf16): C/D layout col=lane&15, row=(lane>>4)*4+reg ----
#pragma unroll
    for (int rt = 0; rt < 4; ++rt) {
#pragma unroll
        for (int reg = 0; reg < 4; ++reg) {
            int row = row0 + rt * 16 + blk * 4 + reg;
            if (row < nrows) {
#pragma unroll
                for (int ct = 0; ct < 4; ++ct)
                    Whb[(size_t)row * 256 + c0 + ct * 16 + r] = f2bf(acc[rt][ct][reg]);
            }
        }
    }
    // ---- s1/s2 write from acc_s: rows of row-tile w, col r: r<8 -> s1[h=r] --
#pragma unroll
    for (int reg = 0; reg < 4; ++reg) {
        int row = row0 + w * 16 + blk * 4 + reg;
        if (row < nrows) {
            if (r < 8) s1[row * NH + r] = acc_s[reg];
            else       s2[row * NH + (r - 8)] = acc_s[reg];
        }
    }
    // ---- fused edge-count: 4 edges per thread ----
    int e0 = (blockIdx.x * 256 + t) * 4;
    if (e0 + 3 < NE) {
        int4 e4 = *(const int4*)&ei[e0];
        atomicAdd(&counts[e4.x], 1);
        atomicAdd(&counts[e4.y], 1);
        atomicAdd(&counts[e4.z], 1);
        atomicAdd(&counts[e4.w], 1);
    } else {
        for (int q = 0; q < 4; ++q)
            if (e0 + q < NE) atomicAdd(&counts[ei[e0 + q]], 1);
    }
}

// ---------------- scan (3-level) ----------------
__global__ __launch_bounds__(256) void k_scanA(const int* __restrict__ counts,
                                               int* __restrict__ part,
                                               int* __restrict__ bsums, int n) {
    __shared__ int lds[256];
    int t = threadIdx.x;
    int base = blockIdx.x * 1024;
    int i0 = base + t * 4;
    int v0 = (i0 + 0 < n) ? counts[i0 + 0] : 0;
    int v1 = (i0 + 1 < n) ? counts[i0 + 1] : 0;
    int v2 = (i0 + 2 < n) ? counts[i0 + 2] : 0;
    int v3 = (i0 + 3 < n) ? counts[i0 + 3] : 0;
    int l0 = v0, l1 = l0 + v1, l2 = l1 + v2, l3 = l2 + v3;
    lds[t] = l3;
    __syncthreads();
    for (int off = 1; off < 256; off <<= 1) {
        int val = lds[t];
        if (t >= off) val += lds[t - off];
        __syncthreads();
        lds[t] = val;
        __syncthreads();
    }
    int excl = (t == 0) ? 0 : lds[t - 1];
    if (i0 + 0 < n) part[i0 + 0] = excl;
    if (i0 + 1 < n) part[i0 + 1] = excl + l0;
    if (i0 + 2 < n) part[i0 + 2] = excl + l1;
    if (i0 + 3 < n) part[i0 + 3] = excl + l2;
    if (t == 255) bsums[blockIdx.x] = lds[255];
}

__global__ void k_scanB(const int* __restrict__ bsums, int* __restrict__ boffs, int nb) {
    __shared__ int s[64];
    int t = threadIdx.x;
    int v = (t < nb) ? bsums[t] : 0;
    s[t] = v;
    __syncthreads();
    for (int off = 1; off < 64; off <<= 1) {
        int x = s[t];
        if (t >= off) x += s[t - off];
        __syncthreads();
        s[t] = x;
        __syncthreads();
    }
    if (t < nb) boffs[t] = s[t] - v;     // exclusive
}

__global__ __launch_bounds__(256) void k_scanC(int* __restrict__ row_ptr,
                                               const int* __restrict__ boffs, int n, int total) {
    int i = blockIdx.x * 256 + threadIdx.x;
    if (i < n) row_ptr[i] += boffs[i >> 10];
    else if (i == n) row_ptr[n] = total;
}

// ------- scatter + logits (bf16), slot via atomicSub(counts) -> no fill -----
__global__ __launch_bounds__(256) void k_scatlog(const int* __restrict__ ei,
                                                 const float* __restrict__ eattr,
                                                 const int* __restrict__ degs,
                                                 const float* __restrict__ s1,
                                                 const float* __restrict__ s2,
                                                 const float* __restrict__ C,
                                                 const int* __restrict__ row_ptr,
                                                 int* __restrict__ counts,
                                                 unsigned short* __restrict__ e_perm,
                                                 int2* __restrict__ de_perm) {
    __shared__ float Cl[NH * FE];
    int t = threadIdx.x;
    if (t < NH * FE) Cl[t] = C[t];
    __syncthreads();
    int e = blockIdx.x * 256 + t;
    if (e >= NE) return;
    int src = ei[e], dst = ei[NE + e];
    int dg = degs[e];
    float scale = rsqrtf((float)(dg > 1 ? dg : 1));
    float ea0 = eattr[(size_t)e * FE + 0];
    float ea1 = eattr[(size_t)e * FE + 1];
    float ea2 = eattr[(size_t)e * FE + 2];
    float ea3 = eattr[(size_t)e * FE + 3];
    float ea4 = eattr[(size_t)e * FE + 4];
    float4 s1a = *(const float4*)&s1[src * NH];
    float4 s1b = *(const float4*)&s1[src * NH + 4];
    float4 s2a = *(const float4*)&s2[dst * NH];
    float4 s2b = *(const float4*)&s2[dst * NH + 4];
    float vs1[8] = {s1a.x, s1a.y, s1a.z, s1a.w, s1b.x, s1b.y, s1b.z, s1b.w};
    float vs2[8] = {s2a.x, s2a.y, s2a.z, s2a.w, s2b.x, s2b.y, s2b.z, s2b.w};
    bf16x8 v;
#pragma unroll
    for (int h = 0; h < NH; ++h) {
        float q = vs1[h] + vs2[h] + ea0 * Cl[h * FE + 0] + ea1 * Cl[h * FE + 1] +
                  ea2 * Cl[h * FE + 2] + ea3 * Cl[h * FE + 3] + ea4 * Cl[h * FE + 4];
        q = q > 0.f ? q : 0.2f * q;
        v[h] = (short)f2bf(q * scale);
    }
    int old = atomicSub(&counts[src], 1);
    int p = row_ptr[src] + old - 1;
    *(bf16x8*)&e_perm[(size_t)p * 8] = v;
    de_perm[p] = make_int2(dst, e);
}

// ------- fused softmax + message aggregation + ELU: ONE WAVE PER NODE -------
__global__ __launch_bounds__(256) void k_smmsg(const int* __restrict__ row_ptr,
                                               const unsigned short* __restrict__ e_perm,
                                               const int2* __restrict__ de_perm,
                                               const unsigned short* __restrict__ Whb,
                                               float* __restrict__ out_alpha,
                                               float* __restrict__ out) {
    __shared__ float al[4][256];
    __shared__ int dl[4][32];
    __shared__ int el[4][32];
    int t = threadIdx.x;
    int w = t >> 6, l = t & 63;
    int n = blockIdx.x * 4 + w;
    if (n >= NN) return;
    int start = row_ptr[n], deg = row_ptr[n + 1] - start;
    int j = l >> 3, h = l & 7;

    // ---- chunk-0 logit cache: edges j+8q, q=0..3 ----
    float vc[4];
#pragma unroll
    for (int q = 0; q < 4; ++q) {
        int b = j + 8 * q;
        vc[q] = (b < deg) ? bf2f(e_perm[(size_t)(start + b) * 8 + h]) : -1e30f;
    }
    // ---- max (clamped at 0) ----
    float mx = 0.f;
#pragma unroll
    for (int q = 0; q < 4; ++q) mx = fmaxf(mx, vc[q]);
    for (int b = 32 + j; b < deg; b += 8)
        mx = fmaxf(mx, bf2f(e_perm[(size_t)(start + b) * 8 + h]));
    mx = fmaxf(mx, __shfl_xor(mx, 8));
    mx = fmaxf(mx, __shfl_xor(mx, 16));
    mx = fmaxf(mx, __shfl_xor(mx, 32));
    float m = mx;
    // ---- sum of exp ----
    float ex[4];
    float sm = 0.f;
#pragma unroll
    for (int q = 0; q < 4; ++q) { ex[q] = __expf(vc[q] - m); sm += ex[q]; }
    for (int b = 32 + j; b < deg; b += 8)
        sm += __expf(bf2f(e_perm[(size_t)(start + b) * 8 + h]) - m);
    sm += __shfl_xor(sm, 8);
    sm += __shfl_xor(sm, 16);
    sm += __shfl_xor(sm, 32);
    float inv = 1.f / (sm + 1e-16f);
    // ---- chunked alpha + aggregation ----
    f32x4 acc = (f32x4)(0.f);
    int hh = l >> 3;
    for (int base = 0; base < deg; base += 32) {
        int cnt = deg - base;
        if (cnt > 32) cnt = 32;
        if (l < cnt) {
            int2 de = de_perm[start + base + l];
            dl[w][l] = de.x;
            el[w][l] = de.y;
        }
        asm volatile("s_waitcnt lgkmcnt(0)" ::: "memory");
#pragma unroll
        for (int q = 0; q < 4; ++q) {
            int b = base + j + 8 * q;
            if (b < deg) {
                float av = (base == 0 ? ex[q]
                                      : __expf(bf2f(e_perm[(size_t)(start + b) * 8 + h]) - m)) * inv;
                al[w][(j + 8 * q) * 8 + h] = av;
                out_alpha[(size_t)el[w][j + 8 * q] * 8 + h] = av;
            }
        }
        asm volatile("s_waitcnt lgkmcnt(0)" ::: "memory");
        for (int jj = 0; jj < cnt; ++jj) {
            int d = dl[w][jj];
            float av = al[w][jj * 8 + hh];
            ushort4 u = *(const ushort4*)&Whb[(size_t)d * 256 + l * 4];
            acc.x += av * bf2f(u.x);
            acc.y += av * bf2f(u.y);
            acc.z += av * bf2f(u.z);
            acc.w += av * bf2f(u.w);
        }
        asm volatile("s_waitcnt lgkmcnt(0)" ::: "memory");
    }
    f32x4 o;
    o.x = acc.x > 0.f ? acc.x : expm1f(acc.x);
    o.y = acc.y > 0.f ? acc.y : expm1f(acc.y);
    o.z = acc.z > 0.f ? acc.z : expm1f(acc.z);
    o.w = acc.w > 0.f ? acc.w : expm1f(acc.w);
    *(f32x4*)&out[(size_t)n * 256 + l * 4] = o;
}

extern "C" void kernel_launch(void* const* d_in, const int* in_sizes, int n_in,
                              void* d_out, int out_size, void* d_ws, size_t ws_size,
                              hipStream_t stream) {
    const float* x     = (const float*)d_in[0];
    const int*   ei    = (const int*)d_in[1];     // [2][E]
    const float* eattr = (const float*)d_in[2];   // [E][5]
    const int*   degs  = (const int*)d_in[3];     // [E]
    const float* W     = (const float*)d_in[4];   // [8][256][32]
    const float* a     = (const float*)d_in[5];   // [8][69]
    const float* Wew   = (const float*)d_in[6];   // [5][5]

    float* out       = (float*)d_out;                    // N*256
    float* out_alpha = out + (size_t)NN * 256;           // E*8

    // bump allocator over d_ws
    char* p = (char*)d_ws;
    auto alloc = [&](size_t bytes) -> char* {
        char* r = p;
        p += (bytes + 255) & ~(size_t)255;
        return r;
    };
    unsigned short* Whb     = (unsigned short*)alloc((size_t)NN * 256 * 2);
    float*          s1      = (float*)alloc((size_t)NN * NH * 4);
    float*          s2      = (float*)alloc((size_t)NN * NH * 4);
    float*          Cm      = (float*)alloc(NH * FE * 4);
    unsigned short* Bh      = (unsigned short*)alloc((size_t)256 * 256 * 2);
    unsigned short* Bl      = (unsigned short*)alloc((size_t)256 * 256 * 2);
    unsigned short* Bsh     = (unsigned short*)alloc((size_t)16 * 256 * 2);
    unsigned short* Bsl     = (unsigned short*)alloc((size_t)16 * 256 * 2);
    int*            counts  = (int*)alloc((size_t)NN * 4);
    int*            row_ptr = (int*)alloc((size_t)(NN + 1) * 4);
    int*            bsums   = (int*)alloc(64 * 4);
    int*            boffs   = (int*)alloc(64 * 4);
    unsigned short* e_perm  = (unsigned short*)alloc((size_t)NE * NH * 2);
    int2*           de_perm = (int2*)alloc((size_t)NE * 8);

    hipMemsetAsync(counts, 0, (size_t)NN * 4, stream);

    k_prep<<<257, 256, 0, stream>>>(W, a, Wew, Cm, Bh, Bl, Bsh, Bsl);
    k_gemm_mfma<<<(NN + 63) / 64, 256, 0, stream>>>(x, Bh, Bl, Bsh, Bsl, Whb, s1, s2,
                                                    ei, counts, NN);
    k_scanA<<<(NN + 1023) / 1024, 256, 0, stream>>>(counts, row_ptr, bsums, NN);
    k_scanB<<<1, 64, 0, stream>>>(bsums, boffs, (NN + 1023) / 1024);
    k_scanC<<<(NN + 1 + 255) / 256, 256, 0, stream>>>(row_ptr, boffs, NN, NE);
    k_scatlog<<<(NE + 255) / 256, 256, 0, stream>>>(ei, eattr, degs, s1, s2, Cm,
                                                    row_ptr, counts, e_perm, de_perm);
    k_smmsg<<<(NN + 3) / 4, 256, 0, stream>>>(row_ptr, e_perm, de_perm, Whb,
                                              out_alpha, out);
}

// Round 9
// 237.673 us; speedup vs baseline: 1.0373x; 1.0373x over previous
//
#include <hip/hip_runtime.h>
#include <hip/hip_bf16.h>
#include <math.h>

#define NN 50000
#define NE 800000
#define FIN 256
#define FOUT 32
#define NH 8
#define FE 5
#define AROW 69          // 2*FOUT + FE

typedef float f32x4 __attribute__((ext_vector_type(4)));
typedef short bf16x8 __attribute__((ext_vector_type(8)));

// round-to-nearest-even fp32 -> bf16 bits
static __device__ __forceinline__ unsigned short f2bf(float f) {
    unsigned u = __float_as_uint(f);
    unsigned r = (u + 0x7FFFu + ((u >> 16) & 1u)) >> 16;
    return (unsigned short)r;
}
static __device__ __forceinline__ float bf2f(unsigned short b) {
    return __uint_as_float(((unsigned)b) << 16);
}

// ------------- prep: C matrix + W split tables + s1/s2 column tables --------
__global__ __launch_bounds__(256) void k_prep(const float* __restrict__ W,
                                              const float* __restrict__ a,
                                              const float* __restrict__ Wew,
                                              float* __restrict__ C,
                                              unsigned short* __restrict__ Bh,
                                              unsigned short* __restrict__ Bl,
                                              unsigned short* __restrict__ Bsh,
                                              unsigned short* __restrict__ Bsl) {
    int t = threadIdx.x;
    if (blockIdx.x == 0) {
        if (t < NH * FE) {
            int h = t / FE, k = t % FE;
            float s = 0.f;
            for (int j = 0; j < FE; ++j) s += a[h * AROW + 2 * FOUT + j] * Wew[j * FE + k];
            C[t] = s;
        }
        int k = t;   // 0..255
        for (int h = 0; h < NH; ++h) {
            float s1v = 0.f, s2v = 0.f;
            for (int o = 0; o < FOUT; ++o) {
                float wv = W[(size_t)h * (FIN * FOUT) + (size_t)k * FOUT + o];
                s1v += wv * a[h * AROW + o];
                s2v += wv * a[h * AROW + FOUT + o];
            }
            unsigned short h1 = f2bf(s1v);
            Bsh[h * 256 + k] = h1;
            Bsl[h * 256 + k] = f2bf(s1v - bf2f(h1));
            unsigned short h2 = f2bf(s2v);
            Bsh[(8 + h) * 256 + k] = h2;
            Bsl[(8 + h) * 256 + k] = f2bf(s2v - bf2f(h2));
        }
    } else {
        int c = blockIdx.x - 1;      // 0..255
        int k = t;
        int h = c >> 5, o = c & 31;
        float f = W[(size_t)h * (FIN * FOUT) + (size_t)k * FOUT + o];
        unsigned short hi = f2bf(f);
        unsigned short lo = f2bf(f - bf2f(hi));
        Bh[c * 256 + k] = hi;
        Bl[c * 256 + k] = lo;
    }
}

// ------- MFMA GEMM, software-pipelined: double-buffered LDS (1 barrier/iter),
// x-slice prefetch 1 iter ahead (regs), B fragments issued pre-barrier so L2
// latency hides under barrier+ds_read. Full unroll -> static LDS indexing.
__global__ __launch_bounds__(256) void k_gemm_mfma(const float* __restrict__ x,
                                                   const unsigned short* __restrict__ Bh,
                                                   const unsigned short* __restrict__ Bl,
                                                   const unsigned short* __restrict__ Bsh,
                                                   const unsigned short* __restrict__ Bsl,
                                                   unsigned short* __restrict__ Whb,
                                                   float* __restrict__ s1,
                                                   float* __restrict__ s2,
                                                   const int* __restrict__ ei,
                                                   int* __restrict__ counts, int nrows) {
    __shared__ __align__(16) unsigned short Ah[2][64 * 56];  // dbuf, row stride 112B
    int t = threadIdx.x;
    int w = t >> 6, l = t & 63;
    int r = l & 15, blk = l >> 4;
    int row0 = blockIdx.x * 64;
    int c0 = w * 64;

    f32x4 acc[4][4];
    f32x4 acc_s = (f32x4)(0.f);
#pragma unroll
    for (int i = 0; i < 4; ++i)
#pragma unroll
        for (int j = 0; j < 4; ++j) acc[i][j] = (f32x4)(0.f);

    int srow = t >> 2, skq = (t & 3) * 8;      // staging: 8 k-elems per thread
    bool arow_ok = (row0 + srow < nrows);
    const float* xp = x + (size_t)(row0 + srow) * FIN + skq;

    // prologue: load k-slice 0
    f32x4 xa0 = (f32x4)(0.f), xa1 = (f32x4)(0.f);
    if (arow_ok) { xa0 = *(const f32x4*)xp; xa1 = *(const f32x4*)(xp + 4); }

#pragma unroll
    for (int ks = 0; ks < 8; ++ks) {
        const int k0 = ks * 32;
        // ---- 1: convert staged regs -> LDS[ks&1] ----
        {
            bf16x8 hi;
            hi[0] = (short)f2bf(xa0.x); hi[1] = (short)f2bf(xa0.y);
            hi[2] = (short)f2bf(xa0.z); hi[3] = (short)f2bf(xa0.w);
            hi[4] = (short)f2bf(xa1.x); hi[5] = (short)f2bf(xa1.y);
            hi[6] = (short)f2bf(xa1.z); hi[7] = (short)f2bf(xa1.w);
            *(bf16x8*)&Ah[ks & 1][srow * 56 + skq] = hi;
        }
        // ---- 2: prefetch next x slice (consumed next iter) ----
        if (ks < 7 && arow_ok) {
            xa0 = *(const f32x4*)(xp + (ks + 1) * 32);
            xa1 = *(const f32x4*)(xp + (ks + 1) * 32 + 4);
        }
        // ---- 3: issue B fragment loads for THIS step (L2-resident) ----
        bf16x8 bh[4], bl[4];
#pragma unroll
        for (int ct = 0; ct < 4; ++ct) {
            int c = c0 + ct * 16 + r;
            bh[ct] = *(const bf16x8*)&Bh[c * 256 + k0 + blk * 8];
            bl[ct] = *(const bf16x8*)&Bl[c * 256 + k0 + blk * 8];
        }
        bf16x8 bsh = *(const bf16x8*)&Bsh[r * 256 + k0 + blk * 8];
        bf16x8 bsl = *(const bf16x8*)&Bsl[r * 256 + k0 + blk * 8];
        // ---- 4: barrier (LDS[ks&1] now complete) ----
        __syncthreads();
        // ---- 5: A fragments from LDS ----
        bf16x8 ah[4];
#pragma unroll
        for (int rt = 0; rt < 4; ++rt)
            ah[rt] = *(const bf16x8*)&Ah[ks & 1][(rt * 16 + r) * 56 + blk * 8];
        // ---- 6: MFMAs ----
#pragma unroll
        for (int ct = 0; ct < 4; ++ct) {
#pragma unroll
            for (int rt = 0; rt < 4; ++rt) {
                acc[rt][ct] = __builtin_amdgcn_mfma_f32_16x16x32_bf16(ah[rt], bh[ct], acc[rt][ct], 0, 0, 0);
                acc[rt][ct] = __builtin_amdgcn_mfma_f32_16x16x32_bf16(ah[rt], bl[ct], acc[rt][ct], 0, 0, 0);
            }
        }
        acc_s = __builtin_amdgcn_mfma_f32_16x16x32_bf16(ah[w], bsh, acc_s, 0, 0, 0);
        acc_s = __builtin_amdgcn_mfma_f32_16x16x32_bf16(ah[w], bsl, acc_s, 0, 0, 0);
    }

    // ---- write Wh (bf16): C/D layout col=lane&15, row=(lane>>4)*4+reg ----
#pragma unroll
    for (int rt = 0; rt < 4; ++rt) {
#pragma unroll
        for (int reg = 0; reg < 4; ++reg) {
            int row = row0 + rt * 16 + blk * 4 + reg;
            if (row < nrows) {
#pragma unroll
                for (int ct = 0; ct < 4; ++ct)
                    Whb[(size_t)row * 256 + c0 + ct * 16 + r] = f2bf(acc[rt][ct][reg]);
            }
        }
    }
    // ---- s1/s2 write from acc_s: rows of row-tile w, col r: r<8 -> s1[h=r] --
#pragma unroll
    for (int reg = 0; reg < 4; ++reg) {
        int row = row0 + w * 16 + blk * 4 + reg;
        if (row < nrows) {
            if (r < 8) s1[row * NH + r] = acc_s[reg];
            else       s2[row * NH + (r - 8)] = acc_s[reg];
        }
    }
    // ---- fused edge-count: 4 edges per thread ----
    int e0 = (blockIdx.x * 256 + t) * 4;
    if (e0 + 3 < NE) {
        int4 e4 = *(const int4*)&ei[e0];
        atomicAdd(&counts[e4.x], 1);
        atomicAdd(&counts[e4.y], 1);
        atomicAdd(&counts[e4.z], 1);
        atomicAdd(&counts[e4.w], 1);
    } else {
        for (int q = 0; q < 4; ++q)
            if (e0 + q < NE) atomicAdd(&counts[ei[e0 + q]], 1);
    }
}

// ---------------- scan (3-level) ----------------
__global__ __launch_bounds__(256) void k_scanA(const int* __restrict__ counts,
                                               int* __restrict__ part,
                                               int* __restrict__ bsums, int n) {
    __shared__ int lds[256];
    int t = threadIdx.x;
    int base = blockIdx.x * 1024;
    int i0 = base + t * 4;
    int v0 = (i0 + 0 < n) ? counts[i0 + 0] : 0;
    int v1 = (i0 + 1 < n) ? counts[i0 + 1] : 0;
    int v2 = (i0 + 2 < n) ? counts[i0 + 2] : 0;
    int v3 = (i0 + 3 < n) ? counts[i0 + 3] : 0;
    int l0 = v0, l1 = l0 + v1, l2 = l1 + v2, l3 = l2 + v3;
    lds[t] = l3;
    __syncthreads();
    for (int off = 1; off < 256; off <<= 1) {
        int val = lds[t];
        if (t >= off) val += lds[t - off];
        __syncthreads();
        lds[t] = val;
        __syncthreads();
    }
    int excl = (t == 0) ? 0 : lds[t - 1];
    if (i0 + 0 < n) part[i0 + 0] = excl;
    if (i0 + 1 < n) part[i0 + 1] = excl + l0;
    if (i0 + 2 < n) part[i0 + 2] = excl + l1;
    if (i0 + 3 < n) part[i0 + 3] = excl + l2;
    if (t == 255) bsums[blockIdx.x] = lds[255];
}

__global__ void k_scanB(const int* __restrict__ bsums, int* __restrict__ boffs, int nb) {
    __shared__ int s[64];
    int t = threadIdx.x;
    int v = (t < nb) ? bsums[t] : 0;
    s[t] = v;
    __syncthreads();
    for (int off = 1; off < 64; off <<= 1) {
        int x = s[t];
        if (t >= off) x += s[t - off];
        __syncthreads();
        s[t] = x;
        __syncthreads();
    }
    if (t < nb) boffs[t] = s[t] - v;     // exclusive
}

__global__ __launch_bounds__(256) void k_scanC(int* __restrict__ row_ptr,
                                               const int* __restrict__ boffs, int n, int total) {
    int i = blockIdx.x * 256 + threadIdx.x;
    if (i < n) row_ptr[i] += boffs[i >> 10];
    else if (i == n) row_ptr[n] = total;
}

// ------- scatter + logits (bf16), slot via atomicSub(counts) -> no fill -----
__global__ __launch_bounds__(256) void k_scatlog(const int* __restrict__ ei,
                                                 const float* __restrict__ eattr,
                                                 const int* __restrict__ degs,
                                                 const float* __restrict__ s1,
                                                 const float* __restrict__ s2,
                                                 const float* __restrict__ C,
                                                 const int* __restrict__ row_ptr,
                                                 int* __restrict__ counts,
                                                 unsigned short* __restrict__ e_perm,
                                                 int2* __restrict__ de_perm) {
    __shared__ float Cl[NH * FE];
    int t = threadIdx.x;
    if (t < NH * FE) Cl[t] = C[t];
    __syncthreads();
    int e = blockIdx.x * 256 + t;
    if (e >= NE) return;
    int src = ei[e], dst = ei[NE + e];
    int dg = degs[e];
    float scale = rsqrtf((float)(dg > 1 ? dg : 1));
    float ea0 = eattr[(size_t)e * FE + 0];
    float ea1 = eattr[(size_t)e * FE + 1];
    float ea2 = eattr[(size_t)e * FE + 2];
    float ea3 = eattr[(size_t)e * FE + 3];
    float ea4 = eattr[(size_t)e * FE + 4];
    float4 s1a = *(const float4*)&s1[src * NH];
    float4 s1b = *(const float4*)&s1[src * NH + 4];
    float4 s2a = *(const float4*)&s2[dst * NH];
    float4 s2b = *(const float4*)&s2[dst * NH + 4];
    float vs1[8] = {s1a.x, s1a.y, s1a.z, s1a.w, s1b.x, s1b.y, s1b.z, s1b.w};
    float vs2[8] = {s2a.x, s2a.y, s2a.z, s2a.w, s2b.x, s2b.y, s2b.z, s2b.w};
    bf16x8 v;
#pragma unroll
    for (int h = 0; h < NH; ++h) {
        float q = vs1[h] + vs2[h] + ea0 * Cl[h * FE + 0] + ea1 * Cl[h * FE + 1] +
                  ea2 * Cl[h * FE + 2] + ea3 * Cl[h * FE + 3] + ea4 * Cl[h * FE + 4];
        q = q > 0.f ? q : 0.2f * q;
        v[h] = (short)f2bf(q * scale);
    }
    int old = atomicSub(&counts[src], 1);
    int p = row_ptr[src] + old - 1;
    *(bf16x8*)&e_perm[(size_t)p * 8] = v;
    de_perm[p] = make_int2(dst, e);
}

// ------- fused softmax + message aggregation + ELU: ONE WAVE PER NODE -------
__global__ __launch_bounds__(256) void k_smmsg(const int* __restrict__ row_ptr,
                                               const unsigned short* __restrict__ e_perm,
                                               const int2* __restrict__ de_perm,
                                               const unsigned short* __restrict__ Whb,
                                               float* __restrict__ out_alpha,
                                               float* __restrict__ out) {
    __shared__ float al[4][256];
    __shared__ int dl[4][32];
    __shared__ int el[4][32];
    int t = threadIdx.x;
    int w = t >> 6, l = t & 63;
    int n = blockIdx.x * 4 + w;
    if (n >= NN) return;
    int start = row_ptr[n], deg = row_ptr[n + 1] - start;
    int j = l >> 3, h = l & 7;

    // ---- chunk-0 logit cache: edges j+8q, q=0..3 ----
    float vc[4];
#pragma unroll
    for (int q = 0; q < 4; ++q) {
        int b = j + 8 * q;
        vc[q] = (b < deg) ? bf2f(e_perm[(size_t)(start + b) * 8 + h]) : -1e30f;
    }
    // ---- max (clamped at 0) ----
    float mx = 0.f;
#pragma unroll
    for (int q = 0; q < 4; ++q) mx = fmaxf(mx, vc[q]);
    for (int b = 32 + j; b < deg; b += 8)
        mx = fmaxf(mx, bf2f(e_perm[(size_t)(start + b) * 8 + h]));
    mx = fmaxf(mx, __shfl_xor(mx, 8));
    mx = fmaxf(mx, __shfl_xor(mx, 16));
    mx = fmaxf(mx, __shfl_xor(mx, 32));
    float m = mx;
    // ---- sum of exp ----
    float ex[4];
    float sm = 0.f;
#pragma unroll
    for (int q = 0; q < 4; ++q) { ex[q] = __expf(vc[q] - m); sm += ex[q]; }
    for (int b = 32 + j; b < deg; b += 8)
        sm += __expf(bf2f(e_perm[(size_t)(start + b) * 8 + h]) - m);
    sm += __shfl_xor(sm, 8);
    sm += __shfl_xor(sm, 16);
    sm += __shfl_xor(sm, 32);
    float inv = 1.f / (sm + 1e-16f);
    // ---- chunked alpha + aggregation ----
    f32x4 acc = (f32x4)(0.f);
    int hh = l >> 3;
    for (int base = 0; base < deg; base += 32) {
        int cnt = deg - base;
        if (cnt > 32) cnt = 32;
        if (l < cnt) {
            int2 de = de_perm[start + base + l];
            dl[w][l] = de.x;
            el[w][l] = de.y;
        }
        asm volatile("s_waitcnt lgkmcnt(0)" ::: "memory");
#pragma unroll
        for (int q = 0; q < 4; ++q) {
            int b = base + j + 8 * q;
            if (b < deg) {
                float av = (base == 0 ? ex[q]
                                      : __expf(bf2f(e_perm[(size_t)(start + b) * 8 + h]) - m)) * inv;
                al[w][(j + 8 * q) * 8 + h] = av;
                out_alpha[(size_t)el[w][j + 8 * q] * 8 + h] = av;
            }
        }
        asm volatile("s_waitcnt lgkmcnt(0)" ::: "memory");
        for (int jj = 0; jj < cnt; ++jj) {
            int d = dl[w][jj];
            float av = al[w][jj * 8 + hh];
            ushort4 u = *(const ushort4*)&Whb[(size_t)d * 256 + l * 4];
            acc.x += av * bf2f(u.x);
            acc.y += av * bf2f(u.y);
            acc.z += av * bf2f(u.z);
            acc.w += av * bf2f(u.w);
        }
        asm volatile("s_waitcnt lgkmcnt(0)" ::: "memory");
    }
    f32x4 o;
    o.x = acc.x > 0.f ? acc.x : expm1f(acc.x);
    o.y = acc.y > 0.f ? acc.y : expm1f(acc.y);
    o.z = acc.z > 0.f ? acc.z : expm1f(acc.z);
    o.w = acc.w > 0.f ? acc.w : expm1f(acc.w);
    *(f32x4*)&out[(size_t)n * 256 + l * 4] = o;
}

extern "C" void kernel_launch(void* const* d_in, const int* in_sizes, int n_in,
                              void* d_out, int out_size, void* d_ws, size_t ws_size,
                              hipStream_t stream) {
    const float* x     = (const float*)d_in[0];
    const int*   ei    = (const int*)d_in[1];     // [2][E]
    const float* eattr = (const float*)d_in[2];   // [E][5]
    const int*   degs  = (const int*)d_in[3];     // [E]
    const float* W     = (const float*)d_in[4];   // [8][256][32]
    const float* a     = (const float*)d_in[5];   // [8][69]
    const float* Wew   = (const float*)d_in[6];   // [5][5]

    float* out       = (float*)d_out;                    // N*256
    float* out_alpha = out + (size_t)NN * 256;           // E*8

    // bump allocator over d_ws
    char* p = (char*)d_ws;
    auto alloc = [&](size_t bytes) -> char* {
        char* r = p;
        p += (bytes + 255) & ~(size_t)255;
        return r;
    };
    unsigned short* Whb     = (unsigned short*)alloc((size_t)NN * 256 * 2);
    float*          s1      = (float*)alloc((size_t)NN * NH * 4);
    float*          s2      = (float*)alloc((size_t)NN * NH * 4);
    float*          Cm      = (float*)alloc(NH * FE * 4);
    unsigned short* Bh      = (unsigned short*)alloc((size_t)256 * 256 * 2);
    unsigned short* Bl      = (unsigned short*)alloc((size_t)256 * 256 * 2);
    unsigned short* Bsh     = (unsigned short*)alloc((size_t)16 * 256 * 2);
    unsigned short* Bsl     = (unsigned short*)alloc((size_t)16 * 256 * 2);
    int*            counts  = (int*)alloc((size_t)NN * 4);
    int*            row_ptr = (int*)alloc((size_t)(NN + 1) * 4);
    int*            bsums   = (int*)alloc(64 * 4);
    int*            boffs   = (int*)alloc(64 * 4);
    unsigned short* e_perm  = (unsigned short*)alloc((size_t)NE * NH * 2);
    int2*           de_perm = (int2*)alloc((size_t)NE * 8);

    hipMemsetAsync(counts, 0, (size_t)NN * 4, stream);

    k_prep<<<257, 256, 0, stream>>>(W, a, Wew, Cm, Bh, Bl, Bsh, Bsl);
    k_gemm_mfma<<<(NN + 63) / 64, 256, 0, stream>>>(x, Bh, Bl, Bsh, Bsl, Whb, s1, s2,
                                                    ei, counts, NN);
    k_scanA<<<(NN + 1023) / 1024, 256, 0, stream>>>(counts, row_ptr, bsums, NN);
    k_scanB<<<1, 64, 0, stream>>>(bsums, boffs, (NN + 1023) / 1024);
    k_scanC<<<(NN + 1 + 255) / 256, 256, 0, stream>>>(row_ptr, boffs, NN, NE);
    k_scatlog<<<(NE + 255) / 256, 256, 0, stream>>>(ei, eattr, degs, s1, s2, Cm,
                                                    row_ptr, counts, e_perm, de_perm);
    k_smmsg<<<(NN + 3) / 4, 256, 0, stream>>>(row_ptr, e_perm, de_perm, Whb,
                                              out_alpha, out);
}